// Round 1
// baseline (75.594 us; speedup 1.0000x reference)
//
#include <hip/hip_runtime.h>

#define KL   19
#define K2   361      // 19*19
#define W    256
#define H    256
#define HW   65536    // 256*256
#define C    3
#define PADL 9
#define B    2

// One wave (64 lanes) per output pixel. Lane l handles kernel taps
// k = l, l+64, ..., giving fully coalesced dword loads of the 189 MB
// kernel tensor (the dominant HBM stream). Input (1.5 MB) is L2-resident;
// reflection indexing is done inline (no padded copy, no workspace needed).
__global__ __launch_bounds__(256) void batchblur_kernel(
    const float* __restrict__ in,     // (B, C, H, W)
    const float* __restrict__ kern,   // (B, HW, 19, 19)
    float* __restrict__ out)          // (B, C, H, W)
{
    const int lane = threadIdx.x & 63;
    const int wave = threadIdx.x >> 6;
    const int p    = blockIdx.x * 4 + wave;   // pixel index in [0, B*HW)

    const int b  = p >> 16;        // p / HW
    const int ij = p & 0xFFFF;     // p % HW
    const int i  = ij >> 8;        // row
    const int j  = ij & 0xFF;      // col

    const float* krow = kern + (size_t)p * K2;
    const float* in_b = in + (size_t)b * (C * HW);

    float acc0 = 0.f, acc1 = 0.f, acc2 = 0.f;

    #pragma unroll
    for (int it = 0; it < 6; ++it) {
        const int k = lane + it * 64;
        if (k < K2) {                 // always true for it<5 (compiler folds)
            const float w = krow[k];
            const int ki = k / KL;
            const int kj = k - ki * KL;
            // reflection pad (no edge repeat): core in [-9, 264]
            int si = i + ki - PADL;
            si = (si < 0) ? -si : si;
            si = (si > H - 1) ? (2 * (H - 1) - si) : si;
            int sj = j + kj - PADL;
            sj = (sj < 0) ? -sj : sj;
            sj = (sj > W - 1) ? (2 * (W - 1) - sj) : sj;
            const float* px = in_b + si * W + sj;
            acc0 += w * px[0];
            acc1 += w * px[HW];
            acc2 += w * px[2 * HW];
        }
    }

    // 64-lane butterfly reduction per channel
    #pragma unroll
    for (int off = 32; off >= 1; off >>= 1) {
        acc0 += __shfl_xor(acc0, off, 64);
        acc1 += __shfl_xor(acc1, off, 64);
        acc2 += __shfl_xor(acc2, off, 64);
    }

    if (lane == 0) {
        const float s = 1.0f / (float)K2;   // divisor l*l
        float* ob = out + (size_t)b * (C * HW) + ij;
        ob[0]      = acc0 * s;
        ob[HW]     = acc1 * s;
        ob[2 * HW] = acc2 * s;
    }
}

extern "C" void kernel_launch(void* const* d_in, const int* in_sizes, int n_in,
                              void* d_out, int out_size, void* d_ws, size_t ws_size,
                              hipStream_t stream) {
    const float* in   = (const float*)d_in[0];   // input  (B,C,H,W)
    const float* kern = (const float*)d_in[1];   // kernel (B,HW,19,19)
    float* out        = (float*)d_out;

    const int npix = B * HW;                     // 131072 pixels
    dim3 grid(npix / 4), block(256);
    hipLaunchKernelGGL(batchblur_kernel, grid, block, 0, stream, in, kern, out);
}

// Round 2
// 67.950 us; speedup vs baseline: 1.1125x; 1.1125x over previous
//
#include <hip/hip_runtime.h>

#define KL   19
#define K2   361
#define W    256
#define H    256
#define HW   65536
#define C    3
#define PADL 9
#define B    2
#define PW   274            // padded H/W (256 + 9 + 9)
#define PHW  (PW * PW)      // 75076

// ---------------------------------------------------------------------------
// Prologue: reflection-pad input (B,C,256,256) -> (B,C,274,274) in workspace.
// 450K threads, ~3.3 MB of traffic, runs in a couple of microseconds.
// ---------------------------------------------------------------------------
__global__ __launch_bounds__(256) void pad_kernel(const float* __restrict__ in,
                                                  float* __restrict__ pad)
{
    const int idx = blockIdx.x * 256 + threadIdx.x;
    const int total = B * C * PHW;
    if (idx >= total) return;
    const int rc = idx % PHW;          // position within one channel plane
    const int bc = idx / PHW;          // b*C + c
    const int r  = rc / PW;
    const int cc = rc - r * PW;
    int sr = r - PADL;  sr = (sr < 0) ? -sr : sr;  sr = (sr > H - 1) ? 2 * (H - 1) - sr : sr;
    int sc = cc - PADL; sc = (sc < 0) ? -sc : sc;  sc = (sc > W - 1) ? 2 * (W - 1) - sc : sc;
    pad[idx] = in[bc * HW + sr * W + sc];
}

// ---------------------------------------------------------------------------
// Main kernel: 16 lanes per output pixel (4 pixels per wave, 16 per block).
// Lane `sub` handles taps t = sub, sub+16, ..., so the 189 MB kernel tensor
// is read with one base address + 23 imm-offset dword loads per lane; each
// wave-instruction covers 4 full 64 B cache lines (perfect coalescing).
// PADDED=true: input pre-padded, zero reflection math in the inner loop.
// ---------------------------------------------------------------------------
template<bool PADDED>
__global__ __launch_bounds__(256) void blur_main(const float* __restrict__ in,
                                                 const float* __restrict__ kern,
                                                 float* __restrict__ out,
                                                 const float* __restrict__ pad)
{
    const int tid = threadIdx.x;
    const int sub = tid & 15;                 // lane within pixel group
    const int q   = tid >> 4;                 // pixel within block [0,16)
    const int p   = (blockIdx.x << 4) + q;    // global pixel in [0, B*HW)

    const int b  = p >> 16;
    const int ij = p & 0xFFFF;
    const int i  = ij >> 8;
    const int j  = ij & 0xFF;

    const float* krow = kern + (size_t)p * K2 + sub;

    float a0 = 0.f, a1 = 0.f, a2 = 0.f;

    if (PADDED) {
        const float* p0c = pad + (size_t)b * (C * PHW) + i * PW + j;
        const float* p1c = p0c + PHW;
        const float* p2c = p0c + 2 * PHW;
        #pragma unroll
        for (int c = 0; c < 23; ++c) {
            const int t = sub + 16 * c;
            if (t < K2) {                     // folded away for c < 22
                const float w  = krow[16 * c];
                const int   ki = t / KL;              // magic-mul divide
                const int  off = t + (PW - KL) * ki;  // = ki*PW + kj
                a0 += w * p0c[off];
                a1 += w * p1c[off];
                a2 += w * p2c[off];
            }
        }
    } else {
        const float* in_b = in + (size_t)b * (C * HW);
        #pragma unroll
        for (int c = 0; c < 23; ++c) {
            const int t = sub + 16 * c;
            if (t < K2) {
                const float w  = krow[16 * c];
                const int   ki = t / KL;
                const int   kj = t - ki * KL;
                int si = i + ki - PADL;
                si = (si < 0) ? -si : si;
                si = (si > H - 1) ? 2 * (H - 1) - si : si;
                int sj = j + kj - PADL;
                sj = (sj < 0) ? -sj : sj;
                sj = (sj > W - 1) ? 2 * (W - 1) - sj : sj;
                const float* px = in_b + si * W + sj;
                a0 += w * px[0];
                a1 += w * px[HW];
                a2 += w * px[2 * HW];
            }
        }
    }

    // reduce across the 16 lanes of this pixel group (4 levels, amortized
    // over the wave's 4 pixels)
    #pragma unroll
    for (int o = 8; o >= 1; o >>= 1) {
        a0 += __shfl_xor(a0, o, 16);
        a1 += __shfl_xor(a1, o, 16);
        a2 += __shfl_xor(a2, o, 16);
    }

    if (sub == 0) {
        const float s = 1.0f / (float)K2;
        float* ob = out + (size_t)b * (C * HW) + ij;
        ob[0]      = a0 * s;
        ob[HW]     = a1 * s;
        ob[2 * HW] = a2 * s;
    }
}

extern "C" void kernel_launch(void* const* d_in, const int* in_sizes, int n_in,
                              void* d_out, int out_size, void* d_ws, size_t ws_size,
                              hipStream_t stream) {
    const float* in   = (const float*)d_in[0];   // (B,C,256,256) f32
    const float* kern = (const float*)d_in[1];   // (B,HW,19,19)  f32
    float* out        = (float*)d_out;

    const size_t pad_bytes = (size_t)B * C * PHW * sizeof(float);   // ~1.8 MB
    const bool use_pad = (d_ws != nullptr) && (ws_size >= pad_bytes);

    const int npix = B * HW;                     // 131072
    dim3 block(256);
    dim3 grid(npix / 16);                        // 16 pixels per block

    if (use_pad) {
        float* padbuf = (float*)d_ws;
        const int total = B * C * PHW;
        hipLaunchKernelGGL(pad_kernel, dim3((total + 255) / 256), block, 0, stream,
                           in, padbuf);
        hipLaunchKernelGGL((blur_main<true>), grid, block, 0, stream,
                           in, kern, out, padbuf);
    } else {
        hipLaunchKernelGGL((blur_main<false>), grid, block, 0, stream,
                           in, kern, out, (const float*)nullptr);
    }
}

// Round 3
// 38.116 us; speedup vs baseline: 1.9832x; 1.7827x over previous
//
#include <hip/hip_runtime.h>

#define KL   19
#define K2   361
#define W    256
#define H    256
#define HW   65536
#define C    3
#define PADL 9
#define B    2
#define TC   34            // tile cols: 16 pixels + 18 halo
#define TPOS (KL * TC)     // 646 spatial positions per tile

// One block = 16 consecutive pixels of one row. 16 lanes per pixel stream the
// per-pixel 19x19 kernel (coalesced dwords, 4 full cache lines per wave-inst).
// The shared 19x34 input window (x3 channels) lives in LDS channel-interleaved
// [pos][4] so each tap is ONE 16B-aligned ds_read of 3 floats.
__global__ __launch_bounds__(256, 8) void blur_fused(
    const float* __restrict__ in,     // (B, C, 256, 256)
    const float* __restrict__ kern,   // (B, HW, 19, 19)
    float* __restrict__ out)          // (B, C, 256, 256)
{
    __shared__ float tile[TPOS * 4];  // 10336 B

    const int tid = threadIdx.x;
    const int pb  = blockIdx.x << 4;      // first pixel of block
    const int b   = pb >> 16;
    const int i   = (pb >> 8) & 255;      // row
    const int j0  = pb & 255;             // first col (multiple of 16)

    // ---- stage input window with fused reflection ----
    // s = pos*4 + ch; ch==3 lanes idle (keeps ds_writes conflict-free).
    const float* in_b = in + (size_t)b * (C * HW);
    for (int s = tid; s < TPOS * 4; s += 256) {
        const int ch  = s & 3;
        const int pos = s >> 2;
        if (ch < 3) {
            const int r  = pos / TC;
            const int cc = pos - r * TC;
            int ro = i + r - PADL;                       // [-9, 264]
            ro = (ro < 0) ? -ro : ro;
            ro = (ro > H - 1) ? 2 * (H - 1) - ro : ro;
            int co = j0 + cc - PADL;
            co = (co < 0) ? -co : co;
            co = (co > W - 1) ? 2 * (W - 1) - co : co;
            tile[s] = in_b[ch * HW + ro * W + co];
        }
    }
    __syncthreads();

    const int sub = tid & 15;             // lane within pixel group
    const int q   = tid >> 4;             // pixel within block
    const int p   = pb + q;
    const float* krow = kern + (size_t)p * K2 + sub;

    // ---- preload all 23 weights (23 loads in flight per lane) ----
    float w[23];
    #pragma unroll
    for (int c = 0; c < 23; ++c) {
        const int t = sub + 16 * c;
        w[c] = (t < K2) ? krow[16 * c] : 0.f;   // guarded only for c==22
    }

    // ---- accumulate from LDS ----
    float a0 = 0.f, a1 = 0.f, a2 = 0.f;
    #pragma unroll
    for (int c = 0; c < 23; ++c) {
        int t = sub + 16 * c;
        if (t > K2 - 1) t = K2 - 1;       // clamp (w==0 there), only c==22
        const int ki  = t / KL;
        const int kj  = t - ki * KL;
        const int pos = ki * TC + kj + q;
        const float* src = &tile[pos * 4];
        a0 += w[c] * src[0];
        a1 += w[c] * src[1];
        a2 += w[c] * src[2];
    }

    // ---- reduce the 16 lanes of each pixel group ----
    #pragma unroll
    for (int o = 8; o >= 1; o >>= 1) {
        a0 += __shfl_xor(a0, o, 16);
        a1 += __shfl_xor(a1, o, 16);
        a2 += __shfl_xor(a2, o, 16);
    }

    if (sub == 0) {
        const float s = 1.0f / (float)K2;
        float* ob = out + (size_t)b * (C * HW) + i * W + j0 + q;
        ob[0]      = a0 * s;
        ob[HW]     = a1 * s;
        ob[2 * HW] = a2 * s;
    }
}

extern "C" void kernel_launch(void* const* d_in, const int* in_sizes, int n_in,
                              void* d_out, int out_size, void* d_ws, size_t ws_size,
                              hipStream_t stream) {
    const float* in   = (const float*)d_in[0];
    const float* kern = (const float*)d_in[1];
    float* out        = (float*)d_out;

    const int npix = B * HW;                 // 131072
    dim3 grid(npix / 16), block(256);        // 8192 blocks
    hipLaunchKernelGGL(blur_fused, grid, block, 0, stream, in, kern, out);
}